// Round 11
// baseline (463.075 us; speedup 1.0000x reference)
//
#include <hip/hip_runtime.h>
#include <hip/hip_bf16.h>

#define N_ROWS 32768
#define D_INP  256
#define NEXP   32
#define D_OUTP 256
#define TROWS  32
#define GROWS  64
#define NBLKF  512   // co-residency guaranteed: LDS 51.5KB<=80KB, VGPR<=256 (launch_bounds), 2 blk/CU

typedef __attribute__((ext_vector_type(4))) float f32x4;
typedef __attribute__((ext_vector_type(8))) short bf16x8;

__device__ inline unsigned short f2b(float f) {
    union { __hip_bfloat16 h; unsigned short u; } cv;
    cv.h = __float2bfloat16(f);
    return cv.u;
}
__device__ inline float b2f(unsigned short u) {
    union { unsigned v; float f; } c; c.v = ((unsigned)u) << 16; return c.f;
}

struct GateSh  { float rA[8448]; float xs[GROWS * 68]; float lsum[NEXP]; int lcnt[NEXP]; };
struct GemmSh  { unsigned short xa[TROWS * 256]; int s_offs[NEXP + 1]; int s_toff[NEXP + 1];
                 int srow[TROWS]; int sslot[TROWS]; float sprob[TROWS]; };
struct BuildSh { int lcnt[NEXP]; int lbase[NEXP]; int soffs[NEXP + 1]; };
union ShU { GateSh g; GemmSh m; BuildSh b; };

// device-scope grid barrier: monotonic counter, no reset (memset 0 each launch).
// __threadfence() = agent-scope fence -> L2 writeback/invalidate (cross-XCD safe).
__device__ __forceinline__ void gbar(int* cnt, int target) {
    __threadfence();
    __syncthreads();
    if (threadIdx.x == 0) {
        atomicAdd(cnt, 1);
        while (atomicAdd(cnt, 0) < target) __builtin_amdgcn_s_sleep(2);
    }
    __syncthreads();
    __threadfence();
}

__global__ __launch_bounds__(256, 2) void moe_fused(
    const float* __restrict__ x, const float* __restrict__ noise,
    const float* __restrict__ gw, const float* __restrict__ gb,
    const float* __restrict__ ew, const float* __restrict__ expb,
    unsigned short* __restrict__ wbT, unsigned short* __restrict__ xb,
    float* __restrict__ tkp, int* __restrict__ tki,
    float* __restrict__ esum, int* __restrict__ ecnt, int* __restrict__ cur0,
    int* __restrict__ bar, int* __restrict__ list,
    unsigned short* __restrict__ y0, unsigned short* __restrict__ y1,
    float* __restrict__ out)
{
    __shared__ ShU sh;
    int tid = threadIdx.x;
    int bid = blockIdx.x;

    // ======================= Phase G: gate (rows [bid*64, +64)) =======================
    {
        int row0 = bid * GROWS;

        #pragma unroll
        for (int it = 0; it < 8; ++it) {
            int q = it * 256 + tid;
            int e = q >> 6;
            int k = (q & 63) * 4;
            float4 v = ((const float4*)gw)[q];
            *(float4*)&sh.g.rA[e * 260 + k] = v;
        }
        if (tid < NEXP) { sh.g.lsum[tid] = 0.f; sh.g.lcnt[tid] = 0; }

        int lane = tid & 63;
        int wid  = tid >> 6;
        int e4 = lane & 7;
        int rq = lane >> 3;

        float acc[8][4];
        #pragma unroll
        for (int m = 0; m < 8; m++)
            #pragma unroll
            for (int n = 0; n < 4; n++) acc[m][n] = 0.f;

        for (int s = 0; s < 4; ++s) {
            __syncthreads();
            #pragma unroll
            for (int it = 0; it < 4; ++it) {
                int q = it * 256 + tid;
                int r = q >> 4;
                int kq = q & 15;
                float4 v = *(const float4*)(x + (size_t)(row0 + r) * D_INP + s * 64 + kq * 4);
                *(float4*)&sh.g.xs[r * 68 + kq * 4] = v;
                unsigned short b[4] = { f2b(v.x), f2b(v.y), f2b(v.z), f2b(v.w) };
                *(ushort4*)(xb + (size_t)(row0 + r) * D_INP + s * 64 + kq * 4) = *(ushort4*)b;
            }
            __syncthreads();
            int ko = s * 64 + wid * 16;
            #pragma unroll
            for (int c = 0; c < 4; ++c) {
                float4 wv[4];
                #pragma unroll
                for (int n = 0; n < 4; n++)
                    wv[n] = *(float4*)&sh.g.rA[(e4 + 8 * n) * 260 + ko + c * 4];
                #pragma unroll
                for (int m = 0; m < 8; m++) {
                    float4 xv = *(float4*)&sh.g.xs[(rq + 8 * m) * 68 + wid * 16 + c * 4];
                    #pragma unroll
                    for (int n = 0; n < 4; n++)
                        acc[m][n] = fmaf(xv.x, wv[n].x,
                                    fmaf(xv.y, wv[n].y,
                                    fmaf(xv.z, wv[n].z,
                                    fmaf(xv.w, wv[n].w, acc[m][n]))));
                }
            }
        }
        __syncthreads();

        {
            int base = (wid * 64 + lane) * 33;
            #pragma unroll
            for (int m = 0; m < 8; m++)
                #pragma unroll
                for (int n = 0; n < 4; n++)
                    sh.g.rA[base + m * 4 + n] = acc[m][n];
        }
        __syncthreads();

        {
            int row = tid >> 2;
            int eo  = (tid & 3) * 8;
            int n   = tid & 3;
            int R = row0 + row;
            int j = (row >> 3) * 4 + n;
            int lpb = (row & 7) * 8;
            float4 nz0 = *(const float4*)(noise + (size_t)R * NEXP + eo);
            float4 nz1 = *(const float4*)(noise + (size_t)R * NEXP + eo + 4);
            float nz[8] = { nz0.x, nz0.y, nz0.z, nz0.w, nz1.x, nz1.y, nz1.z, nz1.w };
            float l[8], p[8];
            #pragma unroll
            for (int i = 0; i < 8; i++) {
                int a = (lpb + i) * 33 + j;
                float v = sh.g.rA[a] + sh.g.rA[2112 + a] + sh.g.rA[4224 + a] + sh.g.rA[6336 + a];
                l[i] = v + gb[eo + i] + 0.1f * nz[i];
            }
            float mx = l[0];
            #pragma unroll
            for (int i = 1; i < 8; i++) mx = fmaxf(mx, l[i]);
            mx = fmaxf(mx, __shfl_xor(mx, 1));
            mx = fmaxf(mx, __shfl_xor(mx, 2));
            float sum = 0.f;
            #pragma unroll
            for (int i = 0; i < 8; i++) { p[i] = expf(l[i] - mx); sum += p[i]; }
            sum += __shfl_xor(sum, 1);
            sum += __shfl_xor(sum, 2);
            float inv = 1.f / sum;
            #pragma unroll
            for (int i = 0; i < 8; i++) p[i] *= inv;

            float bp = p[0]; int bi = eo;
            #pragma unroll
            for (int i = 1; i < 8; i++) if (p[i] > bp) { bp = p[i]; bi = eo + i; }
            #pragma unroll
            for (int s2 = 1; s2 < 4; s2 <<= 1) {
                float op = __shfl_xor(bp, s2); int oi = __shfl_xor(bi, s2);
                if (op > bp || (op == bp && oi < bi)) { bp = op; bi = oi; }
            }
            float bp2 = -1.f; int bi2 = 0;
            #pragma unroll
            for (int i = 0; i < 8; i++) {
                int E = eo + i;
                float q = (E == bi) ? -1.f : p[i];
                if (q > bp2 || (q == bp2 && E < bi2)) { bp2 = q; bi2 = E; }
            }
            #pragma unroll
            for (int s2 = 1; s2 < 4; s2 <<= 1) {
                float op = __shfl_xor(bp2, s2); int oi = __shfl_xor(bi2, s2);
                if (op > bp2 || (op == bp2 && oi < bi2)) { bp2 = op; bi2 = oi; }
            }
            if ((tid & 3) == 0) {
                tkp[R * 2] = bp;  tkp[R * 2 + 1] = bp2;
                tki[R * 2] = bi;  tki[R * 2 + 1] = bi2;
                atomicAdd(&sh.g.lcnt[bi], 1); atomicAdd(&sh.g.lcnt[bi2], 1);
            }
            #pragma unroll
            for (int i = 0; i < 8; i++) atomicAdd(&sh.g.lsum[eo + i], p[i]);
        }

        // fused experts_w fragment transpose (2 frags/thread x 512 blocks = all)
        #pragma unroll
        for (int it = 0; it < 2; ++it) {
            int fid = bid * 512 + it * 256 + tid;
            int row = fid >> 5;
            int kc  = fid & 31;
            const float4* sp = (const float4*)(ew + (size_t)row * D_INP + kc * 8);
            float4 v0 = sp[0], v1 = sp[1];
            unsigned short t[8] = { f2b(v0.x), f2b(v0.y), f2b(v0.z), f2b(v0.w),
                                    f2b(v1.x), f2b(v1.y), f2b(v1.z), f2b(v1.w) };
            int e  = row >> 8;
            int rr = row & 255;
            int q  = rr >> 6;
            int nn = (rr >> 4) & 3;
            int lr = rr & 15;
            int kk = kc >> 2;
            int kg = kc & 3;
            size_t off = ((((size_t)(e * 4 + q) * 8 + kk) * 4 + nn) * 64 + kg * 16 + lr) * 8;
            *(uint4*)(wbT + off) = *(uint4*)t;
        }

        __syncthreads();
        if (tid < NEXP) {
            unsafeAtomicAdd(&esum[tid], sh.g.lsum[tid]);
            atomicAdd(&ecnt[tid], sh.g.lcnt[tid]);
        }
    }

    gbar(bar, NBLKF);   // ---- routing stats complete ----

    // ======================= Phase B: build list (blocks 0..31) =======================
    if (bid < 32) {
        if (tid < NEXP) sh.b.lcnt[tid] = 0;
        if (tid < 32) {
            int c = ecnt[tid];
            int ic = c;
            #pragma unroll
            for (int s = 1; s < 32; s <<= 1) {
                int a = __shfl_up(ic, s, 32);
                if (tid >= s) ic += a;
            }
            sh.b.soffs[tid + 1] = ic;
            if (tid == 0) sh.b.soffs[0] = 0;
        }
        __syncthreads();
        int e0a[4], e1a[4], p0a[4], p1a[4];
        #pragma unroll
        for (int i = 0; i < 4; i++) {
            int r = bid * 1024 + i * 256 + tid;
            e0a[i] = tki[r * 2]; e1a[i] = tki[r * 2 + 1];
            p0a[i] = atomicAdd(&sh.b.lcnt[e0a[i]], 1);
            p1a[i] = atomicAdd(&sh.b.lcnt[e1a[i]], 1);
        }
        __syncthreads();
        if (tid < NEXP) sh.b.lbase[tid] = sh.b.soffs[tid] + atomicAdd(&cur0[tid], sh.b.lcnt[tid]);
        __syncthreads();
        #pragma unroll
        for (int i = 0; i < 4; i++) {
            int r = bid * 1024 + i * 256 + tid;
            list[sh.b.lbase[e0a[i]] + p0a[i]] = r * 2;
            list[sh.b.lbase[e1a[i]] + p1a[i]] = r * 2 + 1;
        }
        if (bid == 0 && tid < 32) {
            float d = esum[tid] * (1.f / N_ROWS) - (1.f / NEXP);
            float v = d * d;
            #pragma unroll
            for (int s = 16; s > 0; s >>= 1) v += __shfl_xor(v, s, 32);
            if (tid == 0) out[(size_t)N_ROWS * D_OUTP] = v;
        }
    }

    gbar(bar, 2 * NBLKF);   // ---- list complete ----

    // ======================= Phase M: grouped expert GEMM =======================
    {
        if (tid < 32) {
            int c = ecnt[tid];
            int ic = c, itc = (c + TROWS - 1) >> 5;
            #pragma unroll
            for (int s = 1; s < 32; s <<= 1) {
                int a  = __shfl_up(ic, s, 32);  if (tid >= s) ic += a;
                int b2 = __shfl_up(itc, s, 32); if (tid >= s) itc += b2;
            }
            sh.m.s_offs[tid + 1] = ic; sh.m.s_toff[tid + 1] = itc;
            if (tid == 0) { sh.m.s_offs[0] = 0; sh.m.s_toff[0] = 0; }
        }
        __syncthreads();
        int ntile = sh.m.s_toff[NEXP];
        int bs = (bid & 7) * 64 + (bid >> 3);   // XCD swizzle: contiguous tiles per XCD

        int wave = tid >> 6;
        int lane = tid & 63;
        int lr = lane & 15;
        int kg = lane >> 4;
        int n0 = wave * 64;
        int aswz = lr & 7;
        int sr = tid >> 3;   // staging: 8 threads/row
        int sc = tid & 7;
        int swz = sr & 7;

        for (int t = bs; t < ntile; t += NBLKF) {
            int e = 0;
            #pragma unroll
            for (int s = 16; s; s >>= 1)
                if (e + s <= 31 && sh.m.s_toff[e + s] <= t) e += s;
            int m0 = sh.m.s_offs[e] + (t - sh.m.s_toff[e]) * TROWS;
            int nr = min(TROWS, sh.m.s_offs[e + 1] - m0);

            __syncthreads();   // previous iteration's xa/srow reads complete
            if (tid < TROWS) {
                if (tid < nr) {
                    int ent = list[m0 + tid];
                    sh.m.srow[tid]  = ent >> 1;
                    sh.m.sslot[tid] = ent & 1;
                    sh.m.sprob[tid] = tkp[ent];
                } else { sh.m.srow[tid] = -1; sh.m.sslot[tid] = 0; sh.m.sprob[tid] = 0.f; }
            }
            __syncthreads();

            // stage A: 8 threads/row, 16B chunks (sc)+8i, chunk-XOR swizzle
            {
                int gr = sh.m.srow[sr]; if (gr < 0) gr = 0;
                const uint4* src = (const uint4*)(xb + (size_t)gr * D_INP);
                uint4* dst = (uint4*)sh.m.xa;
                #pragma unroll
                for (int i = 0; i < 4; ++i) {
                    int c = sc + 8 * i;
                    dst[sr * 32 + (c ^ swz)] = src[c];
                }
            }
            __syncthreads();

            const unsigned short* wbase = wbT + (size_t)(e * 4 + wave) * 32 * 512;
            f32x4 acc[2][4];
            #pragma unroll
            for (int mm = 0; mm < 2; mm++)
                #pragma unroll
                for (int nn = 0; nn < 4; nn++)
                    acc[mm][nn] = (f32x4){0.f, 0.f, 0.f, 0.f};

            #pragma unroll
            for (int kk = 0; kk < 8; kk++) {
                int chunk = kk * 4 + kg;
                bf16x8 a[2], bb[4];
                #pragma unroll
                for (int mm = 0; mm < 2; mm++)
                    a[mm] = *(const bf16x8*)&sh.m.xa[(mm * 16 + lr) * 256 + ((chunk ^ aswz) * 8)];
                #pragma unroll
                for (int nn = 0; nn < 4; nn++)
                    bb[nn] = *(const bf16x8*)(wbase + (kk * 4 + nn) * 512 + lane * 8);
                #pragma unroll
                for (int mm = 0; mm < 2; mm++)
                    #pragma unroll
                    for (int nn = 0; nn < 4; nn++)
                        acc[mm][nn] = __builtin_amdgcn_mfma_f32_16x16x32_bf16(a[mm], bb[nn], acc[mm][nn], 0, 0, 0);
            }
            __syncthreads();   // A reads done; reuse xa as output staging

            {
                float bias[4];
                #pragma unroll
                for (int nn = 0; nn < 4; nn++) bias[nn] = expb[e * 256 + n0 + nn * 16 + lr];
                #pragma unroll
                for (int mm = 0; mm < 2; mm++) {
                    #pragma unroll
                    for (int j = 0; j < 4; j++) {
                        int lrow = mm * 16 + kg * 4 + j;
                        float pp = sh.m.sprob[lrow];
                        #pragma unroll
                        for (int nn = 0; nn < 4; nn++) {
                            float v = (acc[mm][nn][j] + bias[nn]) * pp;
                            sh.m.xa[lrow * 256 + n0 + nn * 16 + lr] = f2b(v);
                        }
                    }
                }
            }
            __syncthreads();

            // store: 8 threads/row, contiguous 16B chunks of the 512B bf16 row
            {
                int gr = sh.m.srow[sr];
                if (gr >= 0) {
                    unsigned short* dstb = (sh.m.sslot[sr] ? y1 : y0) + (size_t)gr * D_OUTP;
                    const uint4* src = (const uint4*)(sh.m.xa + sr * 256);
                    uint4* dst = (uint4*)dstb;
                    #pragma unroll
                    for (int i = 0; i < 4; ++i) {
                        int c = sc + 8 * i;
                        dst[c] = src[c];
                    }
                }
            }
        }
    }

    gbar(bar, 3 * NBLKF);   // ---- y0/y1 complete ----

    // ======================= Phase C: combine out = y0 + y1 =======================
    {
        #pragma unroll
        for (int i = 0; i < 8; ++i) {
            size_t u = ((size_t)bid * 8 + i) * 256 + tid;
            size_t off = u * 8;
            uint4 a = *(const uint4*)(y0 + off);
            uint4 b = *(const uint4*)(y1 + off);
            const unsigned short* ap = (const unsigned short*)&a;
            const unsigned short* bp = (const unsigned short*)&b;
            float4 o0, o1;
            o0.x = b2f(ap[0]) + b2f(bp[0]);
            o0.y = b2f(ap[1]) + b2f(bp[1]);
            o0.z = b2f(ap[2]) + b2f(bp[2]);
            o0.w = b2f(ap[3]) + b2f(bp[3]);
            o1.x = b2f(ap[4]) + b2f(bp[4]);
            o1.y = b2f(ap[5]) + b2f(bp[5]);
            o1.z = b2f(ap[6]) + b2f(bp[6]);
            o1.w = b2f(ap[7]) + b2f(bp[7]);
            *(float4*)(out + off)     = o0;
            *(float4*)(out + off + 4) = o1;
        }
    }
}

// ---------------------------------------------------------------------------
extern "C" void kernel_launch(void* const* d_in, const int* in_sizes, int n_in,
                              void* d_out, int out_size, void* d_ws, size_t ws_size,
                              hipStream_t stream)
{
    const float* x   = (const float*)d_in[0];
    const float* noi = (const float*)d_in[1];
    const float* gw  = (const float*)d_in[2];
    const float* gb  = (const float*)d_in[3];
    const float* ew  = (const float*)d_in[4];
    const float* eb  = (const float*)d_in[5];
    float* out = (float*)d_out;

    char* p = (char*)d_ws;
    unsigned short* xb  = (unsigned short*)p; p += (size_t)N_ROWS * D_INP * 2;
    unsigned short* wbT = (unsigned short*)p; p += (size_t)NEXP * D_OUTP * D_INP * 2;
    unsigned short* y0  = (unsigned short*)p; p += (size_t)N_ROWS * D_OUTP * 2;
    unsigned short* y1  = (unsigned short*)p; p += (size_t)N_ROWS * D_OUTP * 2;
    float* tkp  = (float*)p; p += (size_t)N_ROWS * 2 * 4;
    int*   tki  = (int*)p;   p += (size_t)N_ROWS * 2 * 4;
    int*   list = (int*)p;   p += (size_t)N_ROWS * 2 * 4;
    float* esum = (float*)p; p += 32 * 4;
    int*   ecnt = (int*)p;   p += 32 * 4;
    int*   cur0 = (int*)p;   p += 32 * 4;
    int*   bar  = (int*)p;   p += 4 * 4;

    hipMemsetAsync(esum, 0, (3 * 32 + 4) * 4, stream);   // esum + ecnt + cur0 + bar

    moe_fused<<<NBLKF, 256, 0, stream>>>(x, noi, gw, gb, ew, eb, wbT, xb,
                                         tkp, tki, esum, ecnt, cur0, bar, list,
                                         y0, y1, out);
}